// Round 6
// baseline (442.793 us; speedup 1.0000x reference)
//
#include <hip/hip_runtime.h>

constexpr int B   = 2;
constexpr int T   = 2048;
constexpr int C   = 2048;
constexpr int H   = 32;
constexpr int HKV = 8;
constexpr int D   = 64;
constexpr float SCALE = 0.125f; // 1/sqrt(64)

typedef __attribute__((ext_vector_type(8))) short bf16x8;
typedef __attribute__((ext_vector_type(4))) float f32x4;

__device__ __forceinline__ unsigned short f2bf(float f) {
    unsigned u = __builtin_bit_cast(unsigned, f);
    u += 0x7fff + ((u >> 16) & 1);          // round-to-nearest-even
    return (unsigned short)(u >> 16);
}
__device__ __forceinline__ float bf2f(unsigned short u) {
    unsigned v = (unsigned)u << 16;
    return __builtin_bit_cast(float, v);
}

typedef __attribute__((address_space(1))) const unsigned char ga_t;
typedef __attribute__((address_space(3))) unsigned char lds_t;
__device__ __forceinline__ void gl2lds16(const void* g, void* l) {
    // 16B per lane, dest = wave-uniform base + lane*16
    __builtin_amdgcn_global_load_lds((ga_t*)g, (lds_t*)l, 16, 0, 0);
}

// ---------------------------------------------------------------------------
// Fused fp32 -> bf16 cast of x + all 4 weights (outputs contiguous in ws).
// 8 elems/thread; all segment boundaries are multiples of 8.
// ---------------------------------------------------------------------------
__global__ __launch_bounds__(256) void cast_all_bf16(const float* __restrict__ x,
                                                     const float* __restrict__ wq,
                                                     const float* __restrict__ wk,
                                                     const float* __restrict__ wv,
                                                     const float* __restrict__ wc,
                                                     unsigned short* __restrict__ out) {
    const size_t b0 = (size_t)B * T * C;            // x end
    const size_t b1 = b0 + (size_t)H * D * C;       // Wq end
    const size_t b2 = b1 + (size_t)HKV * D * C;     // Wk end
    const size_t b3 = b2 + (size_t)HKV * D * C;     // Wv end
    size_t i = ((size_t)blockIdx.x * 256 + threadIdx.x) * 8;
    const float* src;
    size_t off;
    if (i < b0)      { src = x;  off = i; }
    else if (i < b1) { src = wq; off = i - b0; }
    else if (i < b2) { src = wk; off = i - b1; }
    else if (i < b3) { src = wv; off = i - b2; }
    else             { src = wc; off = i - b3; }
    float4 a = *(const float4*)(src + off);
    float4 b = *(const float4*)(src + off + 4);
    uint4 r;
    r.x = (unsigned)f2bf(a.x) | ((unsigned)f2bf(a.y) << 16);
    r.y = (unsigned)f2bf(a.z) | ((unsigned)f2bf(a.w) << 16);
    r.z = (unsigned)f2bf(b.x) | ((unsigned)f2bf(b.y) << 16);
    r.w = (unsigned)f2bf(b.z) | ((unsigned)f2bf(b.w) << 16);
    *(uint4*)(out + i) = r;
}

// ---------------------------------------------------------------------------
// bf16 MFMA NT GEMM (round-3 proven, unchanged)
// ---------------------------------------------------------------------------
template <typename OutT>
__device__ __forceinline__ void gemm_mfma_body(const unsigned short* __restrict__ Xh,
                                               const unsigned short* __restrict__ Wh,
                                               OutT* __restrict__ Y,
                                               int Nloc, int K, int bm, int bn) {
    __shared__ __align__(16) unsigned short As[128 * 32];
    __shared__ __align__(16) unsigned short Bs[128 * 32];
    char* AsB = (char*)As;
    char* BsB = (char*)Bs;

    const int tid  = threadIdx.x;
    const int wave = tid >> 6, lane = tid & 63;
    const int wm = (wave >> 1) * 64, wn = (wave & 1) * 64;
    const int m = lane & 15, quad = lane >> 4;

    const int r0 = tid >> 2;
    const int cs = tid & 3;
    const int cg = cs ^ (r0 & 3);
    const int wbase = (tid & 192) * 16;

    const unsigned short* gA = Xh + (size_t)(bm + r0) * K + cg * 8;
    const unsigned short* gB = Wh + (size_t)(bn + r0) * K + cg * 8;
    const size_t rowStep64 = (size_t)64 * K;

    int aoff[4], boff[4];
#pragma unroll
    for (int mt = 0; mt < 4; ++mt) {
        int ra = wm + mt * 16 + m;
        aoff[mt] = ra * 64 + ((quad ^ (ra & 3)) * 16);
        int rb = wn + mt * 16 + m;
        boff[mt] = rb * 64 + ((quad ^ (rb & 3)) * 16);
    }

    f32x4 acc[4][4];
#pragma unroll
    for (int i = 0; i < 4; ++i)
#pragma unroll
        for (int j = 0; j < 4; ++j) acc[i][j] = (f32x4){0.f, 0.f, 0.f, 0.f};

    for (int k0 = 0; k0 < K; k0 += 32) {
        gl2lds16(gA,             AsB + wbase);
        gl2lds16(gA + rowStep64, AsB + 4096 + wbase);
        gl2lds16(gB,             BsB + wbase);
        gl2lds16(gB + rowStep64, BsB + 4096 + wbase);
        gA += 32;
        gB += 32;
        __syncthreads();

        bf16x8 af[4], bfr[4];
#pragma unroll
        for (int mt = 0; mt < 4; ++mt) af[mt]  = *(const bf16x8*)(AsB + aoff[mt]);
#pragma unroll
        for (int nt = 0; nt < 4; ++nt) bfr[nt] = *(const bf16x8*)(BsB + boff[nt]);
#pragma unroll
        for (int mt = 0; mt < 4; ++mt)
#pragma unroll
            for (int nt = 0; nt < 4; ++nt)
                acc[mt][nt] = __builtin_amdgcn_mfma_f32_16x16x32_bf16(af[mt], bfr[nt],
                                                                      acc[mt][nt], 0, 0, 0);
        __syncthreads();
    }

#pragma unroll
    for (int mt = 0; mt < 4; ++mt)
#pragma unroll
        for (int r = 0; r < 4; ++r) {
            size_t row = (size_t)(bm + wm + mt * 16 + quad * 4 + r);
#pragma unroll
            for (int nt = 0; nt < 4; ++nt) {
                int col = bn + wn + nt * 16 + m;
                float v = acc[mt][nt][r];
                if constexpr (sizeof(OutT) == 2)
                    Y[row * Nloc + col] = f2bf(v);
                else
                    Y[row * Nloc + col] = v;
            }
        }
}

__global__ __launch_bounds__(256) void qkv_gemm_bf16(const unsigned short* __restrict__ Xh,
                                                     const unsigned short* __restrict__ Wqh,
                                                     const unsigned short* __restrict__ Wkh,
                                                     const unsigned short* __restrict__ Wvh,
                                                     unsigned short* __restrict__ qh,
                                                     unsigned short* __restrict__ kh,
                                                     unsigned short* __restrict__ vh) {
    int bn0 = blockIdx.x * 128;
    const unsigned short* Wsel;
    unsigned short* Ysel;
    int bnl, Nloc;
    if (bn0 < H * D)                { Wsel = Wqh; Ysel = qh; bnl = bn0;                  Nloc = H * D;   }
    else if (bn0 < H*D + HKV*D)     { Wsel = Wkh; Ysel = kh; bnl = bn0 - H * D;          Nloc = HKV * D; }
    else                            { Wsel = Wvh; Ysel = vh; bnl = bn0 - H*D - HKV*D;    Nloc = HKV * D; }
    gemm_mfma_body<unsigned short>(Xh, Wsel, Ysel, Nloc, C, blockIdx.y * 128, bnl);
}

__global__ __launch_bounds__(256) void out_gemm_bf16(const unsigned short* __restrict__ Xh,
                                                     const unsigned short* __restrict__ Wh,
                                                     float* __restrict__ Y) {
    gemm_mfma_body<float>(Xh, Wh, Y, C, C, blockIdx.y * 128, blockIdx.x * 128);
}

// ---------------------------------------------------------------------------
// Fused RoPE in-place on bf16 q and k (q gets softmax scale * log2e folded in)
// ---------------------------------------------------------------------------
__global__ void rope_fused(unsigned short* __restrict__ qh, unsigned short* __restrict__ kh,
                           const int* __restrict__ pos_ids, float qscale) {
    int idx = blockIdx.x * blockDim.x + threadIdx.x;
    const int qtotal = B * T * H * 32;
    unsigned short* buf;
    int nheads, rel;
    float sc;
    if (idx < qtotal) { buf = qh; nheads = H;   sc = qscale; rel = idx; }
    else              { buf = kh; nheads = HKV; sc = 1.0f;   rel = idx - qtotal; }
    int d = rel & 31;
    int rest = rel >> 5;                 // = (b*T + t)*nheads + h
    int t = (rest / nheads) % T;
    float pos = (float)pos_ids[t];
    int i1 = d >> 1;
    const float NEG_LF = -(2.0f / 64.0f) * 13.287712379549449f; // -2/D * log2(10000)
    float a1 = pos * exp2f(NEG_LF * (float)i1);
    float a2 = pos * exp2f(NEG_LF * (float)(i1 + 16));
    float c1 = cosf(a1), s1 = sinf(a1);
    float c2 = cosf(a2), s2 = sinf(a2);
    size_t base = (size_t)rest * D + d;
    float x1 = bf2f(buf[base]), x2 = bf2f(buf[base + 32]);
    buf[base]      = f2bf((x1 * c1 - x2 * s1) * sc);
    buf[base + 32] = f2bf((x2 * c2 + x1 * s2) * sc);
}

// ---------------------------------------------------------------------------
// V transpose bf16 [b][t][hkv][d] -> [b][hkv][d][t]
// ---------------------------------------------------------------------------
__global__ __launch_bounds__(256) void v_transpose(const unsigned short* __restrict__ vh,
                                                   unsigned short* __restrict__ vtg) {
    __shared__ unsigned short Vs[64][72];
    const int t0 = blockIdx.x * 64;
    const int hkv = blockIdx.y;
    const int b = blockIdx.z;
    const int tid = threadIdx.x;

    for (int e = tid; e < 512; e += 256) {
        int t = e >> 3, d8 = (e & 7) * 8;
        uint4 val = *(const uint4*)(vh + ((size_t)((b * T + t0 + t) * HKV) + hkv) * D + d8);
        unsigned short tmp[8];
        *(uint4*)tmp = val;
#pragma unroll
        for (int i = 0; i < 8; ++i) Vs[d8 + i][t] = tmp[i];
    }
    __syncthreads();
    for (int e = tid; e < 512; e += 256) {
        int d = e >> 3, c = e & 7;
        *(uint4*)(vtg + ((size_t)((b * HKV + hkv) * D) + d) * T + t0 + c * 8) =
            *(const uint4*)&Vs[d][c * 8];
    }
}

// ---------------------------------------------------------------------------
// bf16 MFMA flash attention v3: round-5 compute core (proven) + double-
// buffered K/V staging with prefetch distance 1 and raw-barrier sync:
//   top of iter it: issue gl2lds for tile it+1 into buf^1 (WAR-safe: prior
//     end-barrier), then s_waitcnt vmcnt(4) [tile it's 4 oldest loads done,
//     prefetch stays IN FLIGHT] + s_barrier.
//   end of iter: s_waitcnt lgkmcnt(0) + s_barrier (no vmcnt drain — the
//     thing __syncthreads() can't express).
// Barrier counts are wave-uniform (nIter, pf are block-uniform).
// ---------------------------------------------------------------------------
__global__ __launch_bounds__(256, 4) void flash_attn_mfma(const unsigned short* __restrict__ Qh,
                                                          const unsigned short* __restrict__ Kh,
                                                          const unsigned short* __restrict__ Vtg,
                                                          unsigned short* __restrict__ Yh) {
    __shared__ __align__(16) unsigned short Ks0[64 * 64];
    __shared__ __align__(16) unsigned short Ks1[64 * 64];
    __shared__ __align__(16) unsigned short Vt0[64 * 64];
    __shared__ __align__(16) unsigned short Vt1[64 * 64];
    __shared__ __align__(16) unsigned short Ps[4][16][72]; // per-wave strip, reused per ct

    const int q0 = ((int)gridDim.x - 1 - (int)blockIdx.x) * 128;   // heavy-first
    const int h  = blockIdx.y;
    const int b  = blockIdx.z;
    const int hkv = h >> 2;
    const int tid = threadIdx.x;
    const int wave = tid >> 6;
    const int lane = tid & 63;
    const int m = lane & 15;
    const int quad = lane >> 4;

    // Q B-frags: queries q0 + ct*64 + wave*16 + m
    bf16x8 qa[2][2];
#pragma unroll
    for (int ct = 0; ct < 2; ++ct) {
        const unsigned short* qrow =
            Qh + ((size_t)((b * T + q0 + ct * 64 + wave * 16 + m) * H) + h) * D;
        qa[ct][0] = *(const bf16x8*)(qrow + quad * 8);
        qa[ct][1] = *(const bf16x8*)(qrow + 32 + quad * 8);
    }

    f32x4 o[2][4];
#pragma unroll
    for (int ct = 0; ct < 2; ++ct)
#pragma unroll
        for (int dt = 0; dt < 4; ++dt) o[ct][dt] = (f32x4){0.f, 0.f, 0.f, 0.f};
    float ms[2] = {-1e30f, -1e30f};
    float ls[2] = {0.f, 0.f};

    // staging: thread t -> LDS slot t*16B (row r0=t>>3, chunk cs=t&7),
    // source chunk cg = cs ^ (r0&7)  (XOR applied on the global address)
    const int r0 = tid >> 3, cs = tid & 7, cg = cs ^ (r0 & 7);
    const int wbase = (tid & 192) * 16;
    const unsigned short* gK = Kh + ((size_t)(b * T) * HKV + hkv) * D
                                  + (size_t)r0 * (HKV * D) + cg * 8;
    const unsigned short* gV = Vtg + ((size_t)(b * HKV + hkv) * D) * (size_t)T
                                   + (size_t)r0 * T + cg * 8;

    const int nIter = q0 / 64 + 2;

    // preamble: tile 0 -> buf 0
    gl2lds16(gK,                          (char*)Ks0 + wbase);
    gl2lds16(gK + (size_t)32 * (HKV * D), (char*)Ks0 + 4096 + wbase);
    gl2lds16(gV,                          (char*)Vt0 + wbase);
    gl2lds16(gV + (size_t)32 * T,         (char*)Vt0 + 4096 + wbase);
    gK += (size_t)64 * (HKV * D);
    gV += 64;

    for (int it = 0; it < nIter; ++it) {
        const int k0 = it * 64;
        char* KsB = (it & 1) ? (char*)Ks1 : (char*)Ks0;
        char* VtB = (it & 1) ? (char*)Vt1 : (char*)Vt0;
        const bool pf = (it + 1 < nIter);
        if (pf) {
            char* kd = (it & 1) ? (char*)Ks0 : (char*)Ks1;
            char* vd = (it & 1) ? (char*)Vt0 : (char*)Vt1;
            gl2lds16(gK,                          kd + wbase);
            gl2lds16(gK + (size_t)32 * (HKV * D), kd + 4096 + wbase);
            gl2lds16(gV,                          vd + wbase);
            gl2lds16(gV + (size_t)32 * T,         vd + 4096 + wbase);
            gK += (size_t)64 * (HKV * D);
            gV += 64;
        }
        // RAW: tile it's 4 loads (oldest) must be done; prefetch stays in flight
        if (pf) asm volatile("s_waitcnt vmcnt(4)" ::: "memory");
        else    asm volatile("s_waitcnt vmcnt(0)" ::: "memory");
        asm volatile("s_barrier" ::: "memory");

#pragma unroll
        for (int ct = 0; ct < 2; ++ct) {
            const int qmin = q0 + ct * 64 + wave * 16;
            if (k0 > qmin + 15) continue;          // ct fully masked (wave-uniform)

            // ---- S^T = K · Q^T  (4 key-tiles of 16) ----
            f32x4 s[4];
#pragma unroll
            for (int nt = 0; nt < 4; ++nt) {
                const int kmin = k0 + nt * 16;
                if (kmin > qmin + 15) {            // fully masked tile
                    s[nt] = (f32x4){-1e30f, -1e30f, -1e30f, -1e30f};
                    continue;
                }
                int row = nt * 16 + m;
                const bf16x8 ka0 = *(const bf16x8*)(KsB + row * 128 + ((quad ^ (m & 7)) * 16));
                const bf16x8 ka1 = *(const bf16x8*)(KsB + row * 128 + (((quad + 4) ^ (m & 7)) * 16));
                f32x4 acc = (f32x4){0.f, 0.f, 0.f, 0.f};
                acc = __builtin_amdgcn_mfma_f32_16x16x32_bf16(ka0, qa[ct][0], acc, 0, 0, 0);
                acc = __builtin_amdgcn_mfma_f32_16x16x32_bf16(ka1, qa[ct][1], acc, 0, 0, 0);
                if (kmin + 15 > qmin) {            // diagonal: elementwise mask
                    int c0 = qmin - kmin + m - 4 * quad;   // mask if r > c0
#pragma unroll
                    for (int r = 0; r < 4; ++r)
                        if (r > c0) acc[r] = -1e30f;
                }
                s[nt] = acc;
            }

            // ---- base-2 online softmax (lane owns query m; reduce across quads) ----
            float mx = s[0][0];
#pragma unroll
            for (int nt = 0; nt < 4; ++nt)
#pragma unroll
                for (int r = 0; r < 4; ++r) mx = fmaxf(mx, s[nt][r]);
            mx = fmaxf(mx, __shfl_xor(mx, 16));
            mx = fmaxf(mx, __shfl_xor(mx, 32));
            float mnew = fmaxf(ms[ct], mx);
            float al = exp2f(ms[ct] - mnew);
            ms[ct] = mnew;
            float psum = 0.f;
#pragma unroll
            for (int nt = 0; nt < 4; ++nt)
#pragma unroll
                for (int r = 0; r < 4; ++r) {
                    float p = exp2f(s[nt][r] - mnew);
                    s[nt][r] = p;
                    psum += p;
                }
            psum += __shfl_xor(psum, 16);
            psum += __shfl_xor(psum, 32);
            ls[ct] = ls[ct] * al + psum;

            // ---- P -> wave-private LDS strip (scalar same-type stores) ----
#pragma unroll
            for (int nt = 0; nt < 4; ++nt)
#pragma unroll
                for (int r = 0; r < 4; ++r)
                    Ps[wave][m][nt * 16 + quad * 4 + r] = f2bf(s[nt][r]);

            // ---- alpha transpose (query=m orient -> O-row orient) + rescale ----
            float av[4];
#pragma unroll
            for (int r = 0; r < 4; ++r)
                av[r] = __shfl(al, quad * 20 + r);   // lane with m' = quad*4+r
#pragma unroll
            for (int dt = 0; dt < 4; ++dt)
#pragma unroll
                for (int r = 0; r < 4; ++r) o[ct][dt][r] *= av[r];

            // ---- O += P · V ----
            const bf16x8 pa0 = *(const bf16x8*)&Ps[wave][m][quad * 8];
            const bf16x8 pa1 = *(const bf16x8*)&Ps[wave][m][32 + quad * 8];
#pragma unroll
            for (int dt = 0; dt < 4; ++dt) {
                int vrow = dt * 16 + m;
                const bf16x8 vb0 = *(const bf16x8*)(VtB + vrow * 128 + ((quad ^ (m & 7)) * 16));
                const bf16x8 vb1 = *(const bf16x8*)(VtB + vrow * 128 + (((quad + 4) ^ (m & 7)) * 16));
                o[ct][dt] = __builtin_amdgcn_mfma_f32_16x16x32_bf16(pa0, vb0, o[ct][dt], 0, 0, 0);
                o[ct][dt] = __builtin_amdgcn_mfma_f32_16x16x32_bf16(pa1, vb1, o[ct][dt], 0, 0, 0);
            }
        }

        // WAR: all waves done reading this buf before next prefetch overwrites it.
        // NO vmcnt drain here — the in-flight prefetch crosses this barrier.
        asm volatile("s_waitcnt lgkmcnt(0)" ::: "memory");
        asm volatile("s_barrier" ::: "memory");
    }

    // ---- epilogue: O / l -> bf16 y[b][t][h][d] ----
#pragma unroll
    for (int ct = 0; ct < 2; ++ct) {
#pragma unroll
        for (int r = 0; r < 4; ++r) {
            float lv = __shfl(ls[ct], quad * 20 + r);
            float inv = 1.0f / lv;
            int trow = q0 + ct * 64 + wave * 16 + quad * 4 + r;
            unsigned short* yp = Yh + ((size_t)(b * T + trow) * H + h) * D;
#pragma unroll
            for (int dt = 0; dt < 4; ++dt)
                yp[dt * 16 + m] = f2bf(o[ct][dt][r] * inv);
        }
    }
}

// ---------------------------------------------------------------------------
extern "C" void kernel_launch(void* const* d_in, const int* in_sizes, int n_in,
                              void* d_out, int out_size, void* d_ws, size_t ws_size,
                              hipStream_t stream) {
    const float* x  = (const float*)d_in[0];
    const float* Wq = (const float*)d_in[1];
    const float* Wk = (const float*)d_in[2];
    const float* Wv = (const float*)d_in[3];
    const float* Wc = (const float*)d_in[4];
    const int*  pos = (const int*)d_in[5];
    float* out = (float*)d_out;

    unsigned short* xh  = (unsigned short*)d_ws;           // B*T*C       (contiguous with
    unsigned short* wqh = xh  + (size_t)B * T * C;         //  the 4 weight buffers — the
    unsigned short* wkh = wqh + (size_t)H * D * C;         //  fused cast relies on this)
    unsigned short* wvh = wkh + (size_t)HKV * D * C;
    unsigned short* wch = wvh + (size_t)HKV * D * C;
    unsigned short* qh  = wch + (size_t)C * C;
    unsigned short* kh  = qh  + (size_t)B * T * H * D;
    unsigned short* vh  = kh  + (size_t)B * T * HKV * D;
    unsigned short* vtg = vh  + (size_t)B * T * HKV * D;
    unsigned short* yh  = xh;                              // alias (xh dead after QKV)

    // 1) fused cast fp32 -> bf16 of x + Wq + Wk + Wv + Wc (one launch)
    const size_t cast_total = (size_t)B * T * C + (size_t)(H + 2 * HKV) * D * C + (size_t)C * C;
    cast_all_bf16<<<(unsigned)(cast_total / (256 * 8)), 256, 0, stream>>>(x, Wq, Wk, Wv, Wc, xh);

    // 2) fused QKV projection (bf16 MFMA)
    dim3 g1((H * D + 2 * HKV * D) / 128, (B * T) / 128);
    qkv_gemm_bf16<<<g1, 256, 0, stream>>>(xh, wqh, wkh, wvh, qh, kh, vh);

    // 3) fused RoPE on q (scale folded) + k; V transpose
    const float QSCALE = SCALE * 1.4426950408889634f;  // SCALE * log2(e)
    rope_fused<<<(B * T * (H + HKV) * 32) / 256, 256, 0, stream>>>(qh, kh, pos, QSCALE);
    v_transpose<<<dim3(T / 64, HKV, B), 256, 0, stream>>>(vh, vtg);

    // 4) causal GQA flash attention (double-buffered, prefetch distance 1)
    dim3 g2(T / 128, H, B);
    flash_attn_mfma<<<g2, 256, 0, stream>>>(qh, kh, vtg, yh);

    // 5) output projection
    dim3 g3(C / 128, (B * T) / 128);
    out_gemm_bf16<<<g3, 256, 0, stream>>>(yh, wch, out);
}

// Round 7
// 399.051 us; speedup vs baseline: 1.1096x; 1.1096x over previous
//
#include <hip/hip_runtime.h>

constexpr int B   = 2;
constexpr int T   = 2048;
constexpr int C   = 2048;
constexpr int H   = 32;
constexpr int HKV = 8;
constexpr int D   = 64;
constexpr float SCALE = 0.125f; // 1/sqrt(64)

typedef __attribute__((ext_vector_type(8))) short bf16x8;
typedef __attribute__((ext_vector_type(4))) float f32x4;

__device__ __forceinline__ unsigned short f2bf(float f) {
    unsigned u = __builtin_bit_cast(unsigned, f);
    u += 0x7fff + ((u >> 16) & 1);          // round-to-nearest-even
    return (unsigned short)(u >> 16);
}
__device__ __forceinline__ float bf2f(unsigned short u) {
    unsigned v = (unsigned)u << 16;
    return __builtin_bit_cast(float, v);
}

typedef __attribute__((address_space(1))) const unsigned char ga_t;
typedef __attribute__((address_space(3))) unsigned char lds_t;
__device__ __forceinline__ void gl2lds16(const void* g, void* l) {
    // 16B per lane, dest = wave-uniform base + lane*16
    __builtin_amdgcn_global_load_lds((ga_t*)g, (lds_t*)l, 16, 0, 0);
}

// ---------------------------------------------------------------------------
// Fused fp32 -> bf16 cast of x + all 4 weights (outputs contiguous in ws).
// ---------------------------------------------------------------------------
__global__ __launch_bounds__(256) void cast_all_bf16(const float* __restrict__ x,
                                                     const float* __restrict__ wq,
                                                     const float* __restrict__ wk,
                                                     const float* __restrict__ wv,
                                                     const float* __restrict__ wc,
                                                     unsigned short* __restrict__ out) {
    const size_t b0 = (size_t)B * T * C;            // x end
    const size_t b1 = b0 + (size_t)H * D * C;       // Wq end
    const size_t b2 = b1 + (size_t)HKV * D * C;     // Wk end
    const size_t b3 = b2 + (size_t)HKV * D * C;     // Wv end
    size_t i = ((size_t)blockIdx.x * 256 + threadIdx.x) * 8;
    const float* src;
    size_t off;
    if (i < b0)      { src = x;  off = i; }
    else if (i < b1) { src = wq; off = i - b0; }
    else if (i < b2) { src = wk; off = i - b1; }
    else if (i < b3) { src = wv; off = i - b2; }
    else             { src = wc; off = i - b3; }
    float4 a = *(const float4*)(src + off);
    float4 b = *(const float4*)(src + off + 4);
    uint4 r;
    r.x = (unsigned)f2bf(a.x) | ((unsigned)f2bf(a.y) << 16);
    r.y = (unsigned)f2bf(a.z) | ((unsigned)f2bf(a.w) << 16);
    r.z = (unsigned)f2bf(b.x) | ((unsigned)f2bf(b.y) << 16);
    r.w = (unsigned)f2bf(b.z) | ((unsigned)f2bf(b.w) << 16);
    *(uint4*)(out + i) = r;
}

// ---------------------------------------------------------------------------
// bf16 MFMA NT GEMM (round-3 proven, unchanged)
// ---------------------------------------------------------------------------
template <typename OutT>
__device__ __forceinline__ void gemm_mfma_body(const unsigned short* __restrict__ Xh,
                                               const unsigned short* __restrict__ Wh,
                                               OutT* __restrict__ Y,
                                               int Nloc, int K, int bm, int bn) {
    __shared__ __align__(16) unsigned short As[128 * 32];
    __shared__ __align__(16) unsigned short Bs[128 * 32];
    char* AsB = (char*)As;
    char* BsB = (char*)Bs;

    const int tid  = threadIdx.x;
    const int wave = tid >> 6, lane = tid & 63;
    const int wm = (wave >> 1) * 64, wn = (wave & 1) * 64;
    const int m = lane & 15, quad = lane >> 4;

    const int r0 = tid >> 2;
    const int cs = tid & 3;
    const int cg = cs ^ (r0 & 3);
    const int wbase = (tid & 192) * 16;

    const unsigned short* gA = Xh + (size_t)(bm + r0) * K + cg * 8;
    const unsigned short* gB = Wh + (size_t)(bn + r0) * K + cg * 8;
    const size_t rowStep64 = (size_t)64 * K;

    int aoff[4], boff[4];
#pragma unroll
    for (int mt = 0; mt < 4; ++mt) {
        int ra = wm + mt * 16 + m;
        aoff[mt] = ra * 64 + ((quad ^ (ra & 3)) * 16);
        int rb = wn + mt * 16 + m;
        boff[mt] = rb * 64 + ((quad ^ (rb & 3)) * 16);
    }

    f32x4 acc[4][4];
#pragma unroll
    for (int i = 0; i < 4; ++i)
#pragma unroll
        for (int j = 0; j < 4; ++j) acc[i][j] = (f32x4){0.f, 0.f, 0.f, 0.f};

    for (int k0 = 0; k0 < K; k0 += 32) {
        gl2lds16(gA,             AsB + wbase);
        gl2lds16(gA + rowStep64, AsB + 4096 + wbase);
        gl2lds16(gB,             BsB + wbase);
        gl2lds16(gB + rowStep64, BsB + 4096 + wbase);
        gA += 32;
        gB += 32;
        __syncthreads();

        bf16x8 af[4], bfr[4];
#pragma unroll
        for (int mt = 0; mt < 4; ++mt) af[mt]  = *(const bf16x8*)(AsB + aoff[mt]);
#pragma unroll
        for (int nt = 0; nt < 4; ++nt) bfr[nt] = *(const bf16x8*)(BsB + boff[nt]);
#pragma unroll
        for (int mt = 0; mt < 4; ++mt)
#pragma unroll
            for (int nt = 0; nt < 4; ++nt)
                acc[mt][nt] = __builtin_amdgcn_mfma_f32_16x16x32_bf16(af[mt], bfr[nt],
                                                                      acc[mt][nt], 0, 0, 0);
        __syncthreads();
    }

#pragma unroll
    for (int mt = 0; mt < 4; ++mt)
#pragma unroll
        for (int r = 0; r < 4; ++r) {
            size_t row = (size_t)(bm + wm + mt * 16 + quad * 4 + r);
#pragma unroll
            for (int nt = 0; nt < 4; ++nt) {
                int col = bn + wn + nt * 16 + m;
                float v = acc[mt][nt][r];
                if constexpr (sizeof(OutT) == 2)
                    Y[row * Nloc + col] = f2bf(v);
                else
                    Y[row * Nloc + col] = v;
            }
        }
}

__global__ __launch_bounds__(256) void qkv_gemm_bf16(const unsigned short* __restrict__ Xh,
                                                     const unsigned short* __restrict__ Wqh,
                                                     const unsigned short* __restrict__ Wkh,
                                                     const unsigned short* __restrict__ Wvh,
                                                     unsigned short* __restrict__ qh,
                                                     unsigned short* __restrict__ kh,
                                                     unsigned short* __restrict__ vh) {
    int bn0 = blockIdx.x * 128;
    const unsigned short* Wsel;
    unsigned short* Ysel;
    int bnl, Nloc;
    if (bn0 < H * D)                { Wsel = Wqh; Ysel = qh; bnl = bn0;                  Nloc = H * D;   }
    else if (bn0 < H*D + HKV*D)     { Wsel = Wkh; Ysel = kh; bnl = bn0 - H * D;          Nloc = HKV * D; }
    else                            { Wsel = Wvh; Ysel = vh; bnl = bn0 - H*D - HKV*D;    Nloc = HKV * D; }
    gemm_mfma_body<unsigned short>(Xh, Wsel, Ysel, Nloc, C, blockIdx.y * 128, bnl);
}

__global__ __launch_bounds__(256) void out_gemm_bf16(const unsigned short* __restrict__ Xh,
                                                     const unsigned short* __restrict__ Wh,
                                                     float* __restrict__ Y) {
    gemm_mfma_body<float>(Xh, Wh, Y, C, C, blockIdx.y * 128, blockIdx.x * 128);
}

// ---------------------------------------------------------------------------
// Fused RoPE in-place on bf16 q and k (q gets softmax scale * log2e folded in)
// ---------------------------------------------------------------------------
__global__ void rope_fused(unsigned short* __restrict__ qh, unsigned short* __restrict__ kh,
                           const int* __restrict__ pos_ids, float qscale) {
    int idx = blockIdx.x * blockDim.x + threadIdx.x;
    const int qtotal = B * T * H * 32;
    unsigned short* buf;
    int nheads, rel;
    float sc;
    if (idx < qtotal) { buf = qh; nheads = H;   sc = qscale; rel = idx; }
    else              { buf = kh; nheads = HKV; sc = 1.0f;   rel = idx - qtotal; }
    int d = rel & 31;
    int rest = rel >> 5;                 // = (b*T + t)*nheads + h
    int t = (rest / nheads) % T;
    float pos = (float)pos_ids[t];
    int i1 = d >> 1;
    const float NEG_LF = -(2.0f / 64.0f) * 13.287712379549449f; // -2/D * log2(10000)
    float a1 = pos * exp2f(NEG_LF * (float)i1);
    float a2 = pos * exp2f(NEG_LF * (float)(i1 + 16));
    float c1 = cosf(a1), s1 = sinf(a1);
    float c2 = cosf(a2), s2 = sinf(a2);
    size_t base = (size_t)rest * D + d;
    float x1 = bf2f(buf[base]), x2 = bf2f(buf[base + 32]);
    buf[base]      = f2bf((x1 * c1 - x2 * s1) * sc);
    buf[base + 32] = f2bf((x2 * c2 + x1 * s2) * sc);
}

// ---------------------------------------------------------------------------
// V transpose bf16 [b][t][hkv][d] -> [b][hkv][d][t]
// ---------------------------------------------------------------------------
__global__ __launch_bounds__(256) void v_transpose(const unsigned short* __restrict__ vh,
                                                   unsigned short* __restrict__ vtg) {
    __shared__ unsigned short Vs[64][72];
    const int t0 = blockIdx.x * 64;
    const int hkv = blockIdx.y;
    const int b = blockIdx.z;
    const int tid = threadIdx.x;

    for (int e = tid; e < 512; e += 256) {
        int t = e >> 3, d8 = (e & 7) * 8;
        uint4 val = *(const uint4*)(vh + ((size_t)((b * T + t0 + t) * HKV) + hkv) * D + d8);
        unsigned short tmp[8];
        *(uint4*)tmp = val;
#pragma unroll
        for (int i = 0; i < 8; ++i) Vs[d8 + i][t] = tmp[i];
    }
    __syncthreads();
    for (int e = tid; e < 512; e += 256) {
        int d = e >> 3, c = e & 7;
        *(uint4*)(vtg + ((size_t)((b * HKV + hkv) * D) + d) * T + t0 + c * 8) =
            *(const uint4*)&Vs[d][c * 8];
    }
}

// ---------------------------------------------------------------------------
// bf16 MFMA flash attention v4: round-5 proven core (single-buffered
// __syncthreads K-loop — R6 showed manual vmcnt pipelining regresses),
// occupancy-tuned: 64-query blocks (grid 2048), Ps strip shrunk to 16 rows
// -> LDS 25600 B -> 6 blocks/CU (R5 was 4, grid-limited).
// ---------------------------------------------------------------------------
__global__ __launch_bounds__(256, 6) void flash_attn_mfma(const unsigned short* __restrict__ Qh,
                                                          const unsigned short* __restrict__ Kh,
                                                          const unsigned short* __restrict__ Vtg,
                                                          unsigned short* __restrict__ Yh) {
    __shared__ __align__(16) unsigned short Ks[64 * 64];   // [key][d], XOR-swizzled chunks
    __shared__ __align__(16) unsigned short Vt[64 * 64];   // [d][key], XOR-swizzled chunks
    __shared__ __align__(16) unsigned short Ps[4][16][72]; // per-wave P strip [query][key]

    const int q0 = ((int)gridDim.x - 1 - (int)blockIdx.x) * 64;   // heavy-first
    const int h  = blockIdx.y;
    const int b  = blockIdx.z;
    const int hkv = h >> 2;
    const int tid = threadIdx.x;
    const int wave = tid >> 6;
    const int lane = tid & 63;
    const int m = lane & 15;
    const int quad = lane >> 4;

    // Q B-frags: this wave's 16 queries q0 + wave*16 + m (resident whole kernel)
    const unsigned short* qrow = Qh + ((size_t)((b * T + q0 + wave * 16 + m) * H) + h) * D;
    const bf16x8 qa0 = *(const bf16x8*)(qrow + quad * 8);
    const bf16x8 qa1 = *(const bf16x8*)(qrow + 32 + quad * 8);

    f32x4 o[4];
#pragma unroll
    for (int dt = 0; dt < 4; ++dt) o[dt] = (f32x4){0.f, 0.f, 0.f, 0.f};
    float ms = -1e30f, ls = 0.f;

    // staging: thread t -> LDS slot t*16B (row r0=t>>3, chunk cs=t&7),
    // source chunk cg = cs ^ (r0&7)  (XOR applied on the global address)
    const int r0 = tid >> 3, cs = tid & 7, cg = cs ^ (r0 & 7);
    const int wbase = (tid & 192) * 16;
    const unsigned short* gK = Kh + ((size_t)(b * T) * HKV + hkv) * D
                                  + (size_t)r0 * (HKV * D) + cg * 8;
    const unsigned short* gV = Vtg + ((size_t)(b * HKV + hkv) * D) * (size_t)T
                                   + (size_t)r0 * T + cg * 8;
    char* KsB = (char*)Ks;
    char* VtB = (char*)Vt;

    const int qmin = q0 + wave * 16;

    for (int k0 = 0; k0 <= q0; k0 += 64) {
        gl2lds16(gK,                          KsB + wbase);
        gl2lds16(gK + (size_t)32 * (HKV * D), KsB + 4096 + wbase);
        gl2lds16(gV,                          VtB + wbase);
        gl2lds16(gV + (size_t)32 * T,         VtB + 4096 + wbase);
        gK += (size_t)64 * (HKV * D);
        gV += 64;
        __syncthreads();

        // ---- S^T = K · Q^T  (4 key-tiles of 16) ----
        f32x4 s[4];
#pragma unroll
        for (int nt = 0; nt < 4; ++nt) {
            const int kmin = k0 + nt * 16;
            if (kmin > qmin + 15) {            // fully masked tile
                s[nt] = (f32x4){-1e30f, -1e30f, -1e30f, -1e30f};
                continue;
            }
            int row = nt * 16 + m;
            const bf16x8 ka0 = *(const bf16x8*)(KsB + row * 128 + ((quad ^ (m & 7)) * 16));
            const bf16x8 ka1 = *(const bf16x8*)(KsB + row * 128 + (((quad + 4) ^ (m & 7)) * 16));
            f32x4 acc = (f32x4){0.f, 0.f, 0.f, 0.f};
            acc = __builtin_amdgcn_mfma_f32_16x16x32_bf16(ka0, qa0, acc, 0, 0, 0);
            acc = __builtin_amdgcn_mfma_f32_16x16x32_bf16(ka1, qa1, acc, 0, 0, 0);
            if (kmin + 15 > qmin) {            // diagonal: elementwise mask
                int c0 = qmin - kmin + m - 4 * quad;   // mask if r > c0
#pragma unroll
                for (int r = 0; r < 4; ++r)
                    if (r > c0) acc[r] = -1e30f;
            }
            s[nt] = acc;
        }

        // ---- base-2 online softmax (lane owns query m; reduce across quads) ----
        float mx = s[0][0];
#pragma unroll
        for (int nt = 0; nt < 4; ++nt)
#pragma unroll
            for (int r = 0; r < 4; ++r) mx = fmaxf(mx, s[nt][r]);
        mx = fmaxf(mx, __shfl_xor(mx, 16));
        mx = fmaxf(mx, __shfl_xor(mx, 32));
        float mnew = fmaxf(ms, mx);
        float al = exp2f(ms - mnew);
        ms = mnew;
        float psum = 0.f;
#pragma unroll
        for (int nt = 0; nt < 4; ++nt)
#pragma unroll
            for (int r = 0; r < 4; ++r) {
                float p = exp2f(s[nt][r] - mnew);
                s[nt][r] = p;
                psum += p;
            }
        psum += __shfl_xor(psum, 16);
        psum += __shfl_xor(psum, 32);
        ls = ls * al + psum;

        // ---- P -> wave-private LDS strip (scalar same-type stores) ----
#pragma unroll
        for (int nt = 0; nt < 4; ++nt)
#pragma unroll
            for (int r = 0; r < 4; ++r)
                Ps[wave][m][nt * 16 + quad * 4 + r] = f2bf(s[nt][r]);

        // ---- alpha transpose (query=m orient -> O-row orient) + rescale ----
        float av[4];
#pragma unroll
        for (int r = 0; r < 4; ++r)
            av[r] = __shfl(al, quad * 20 + r);   // lane with m' = quad*4+r
#pragma unroll
        for (int dt = 0; dt < 4; ++dt)
#pragma unroll
            for (int r = 0; r < 4; ++r) o[dt][r] *= av[r];

        // ---- O += P · V ----
        const bf16x8 pa0 = *(const bf16x8*)&Ps[wave][m][quad * 8];
        const bf16x8 pa1 = *(const bf16x8*)&Ps[wave][m][32 + quad * 8];
#pragma unroll
        for (int dt = 0; dt < 4; ++dt) {
            int vrow = dt * 16 + m;
            const bf16x8 vb0 = *(const bf16x8*)(VtB + vrow * 128 + ((quad ^ (m & 7)) * 16));
            const bf16x8 vb1 = *(const bf16x8*)(VtB + vrow * 128 + (((quad + 4) ^ (m & 7)) * 16));
            o[dt] = __builtin_amdgcn_mfma_f32_16x16x32_bf16(pa0, vb0, o[dt], 0, 0, 0);
            o[dt] = __builtin_amdgcn_mfma_f32_16x16x32_bf16(pa1, vb1, o[dt], 0, 0, 0);
        }
        __syncthreads();   // protect Ks/Vt before restage
    }

    // ---- epilogue: O / l -> bf16 y[b][t][h][d] ----
#pragma unroll
    for (int r = 0; r < 4; ++r) {
        float lv = __shfl(ls, quad * 20 + r);
        float inv = 1.0f / lv;
        int trow = q0 + wave * 16 + quad * 4 + r;
        unsigned short* yp = Yh + ((size_t)(b * T + trow) * H + h) * D;
#pragma unroll
        for (int dt = 0; dt < 4; ++dt)
            yp[dt * 16 + m] = f2bf(o[dt][r] * inv);
    }
}

// ---------------------------------------------------------------------------
extern "C" void kernel_launch(void* const* d_in, const int* in_sizes, int n_in,
                              void* d_out, int out_size, void* d_ws, size_t ws_size,
                              hipStream_t stream) {
    const float* x  = (const float*)d_in[0];
    const float* Wq = (const float*)d_in[1];
    const float* Wk = (const float*)d_in[2];
    const float* Wv = (const float*)d_in[3];
    const float* Wc = (const float*)d_in[4];
    const int*  pos = (const int*)d_in[5];
    float* out = (float*)d_out;

    unsigned short* xh  = (unsigned short*)d_ws;           // contiguous with the 4 weight
    unsigned short* wqh = xh  + (size_t)B * T * C;         // buffers — fused cast relies on it
    unsigned short* wkh = wqh + (size_t)H * D * C;
    unsigned short* wvh = wkh + (size_t)HKV * D * C;
    unsigned short* wch = wvh + (size_t)HKV * D * C;
    unsigned short* qh  = wch + (size_t)C * C;
    unsigned short* kh  = qh  + (size_t)B * T * H * D;
    unsigned short* vh  = kh  + (size_t)B * T * HKV * D;
    unsigned short* vtg = vh  + (size_t)B * T * HKV * D;
    unsigned short* yh  = xh;                              // alias (xh dead after QKV)

    // 1) fused cast fp32 -> bf16 of x + Wq + Wk + Wv + Wc (one launch)
    const size_t cast_total = (size_t)B * T * C + (size_t)(H + 2 * HKV) * D * C + (size_t)C * C;
    cast_all_bf16<<<(unsigned)(cast_total / (256 * 8)), 256, 0, stream>>>(x, Wq, Wk, Wv, Wc, xh);

    // 2) fused QKV projection (bf16 MFMA)
    dim3 g1((H * D + 2 * HKV * D) / 128, (B * T) / 128);
    qkv_gemm_bf16<<<g1, 256, 0, stream>>>(xh, wqh, wkh, wvh, qh, kh, vh);

    // 3) fused RoPE on q (scale folded) + k; V transpose
    const float QSCALE = SCALE * 1.4426950408889634f;  // SCALE * log2(e)
    rope_fused<<<(B * T * (H + HKV) * 32) / 256, 256, 0, stream>>>(qh, kh, pos, QSCALE);
    v_transpose<<<dim3(T / 64, HKV, B), 256, 0, stream>>>(vh, vtg);

    // 4) causal GQA flash attention (64-q blocks, 6 blocks/CU)
    dim3 g2(T / 64, H, B);
    flash_attn_mfma<<<g2, 256, 0, stream>>>(qh, kh, vtg, yh);

    // 5) output projection
    dim3 g3(C / 128, (B * T) / 128);
    out_gemm_bf16<<<g3, 256, 0, stream>>>(yh, wch, out);
}